// Round 13
// baseline (165.341 us; speedup 1.0000x reference)
//
#include <hip/hip_runtime.h>
#include <stdint.h>

typedef __fp16 fp16x2 __attribute__((ext_vector_type(2)));
typedef _Float16 half4 __attribute__((ext_vector_type(4)));
typedef _Float16 half8 __attribute__((ext_vector_type(8)));
typedef float f32x4 __attribute__((ext_vector_type(4)));

#define NS 4096
#define NTOT 8192
#define DD 256
#define NPERS 256   // persistent blocks: 1 per CU, 1024 threads (16 waves)
#define NTILE 2080  // 128x128 tiles: br-major strip list

// X16 "tiled4" layout: addr(r,k) = (r>>4)*4096 + (k>>3)*128 + (r&15)*8 + (k&7)
// -> 16-row full-K panel = contiguous 8KB; a 128-row strip = 64KB linear.

// workspace layout (bytes)
#define OFF_X16   0                        // 4 MB fp16 (tiled4)
#define OFF_SQ    (4*1024*1024)            // 8192 floats
#define OFF_SQP   (OFF_SQ + 32*1024)       // 8192 floats: -cl2*sq (premultiplied)
#define OFF_COLP  (OFF_SQP + 32*1024)      // 256*256 floats
#define OFF_BP    (OFF_COLP + 256*1024)    // 256 floats
#define OFF_SCAL  (OFF_BP + 4096)          // 1 float (cl2)

// cumulative tiles before strip br (br<32: SS tri (br+1) then 32 ST;
// br>=32: TT tri (br-31))
__device__ __forceinline__ int cumtiles(int br) {
    return (br <= 32) ? (br * br + 65 * br) / 2
                      : 1552 + ((br - 32) * (br - 31)) / 2;
}

// ---------------------------------------------------------------- K1: prep
__global__ __launch_bounds__(256) void mmd_prep(const float* __restrict__ S,
                                                const float* __restrict__ T,
                                                _Float16* __restrict__ X16,
                                                float* __restrict__ sq,
                                                float* __restrict__ colpart) {
    __shared__ _Float16 tile[16][264];     // +8 halves pad: conflict-free reorder
    __shared__ float cl[4][256];
    const int b = blockIdx.x, tid = threadIdx.x;
    const int lane = tid & 63, w = tid >> 6;
    f32x4 cacc = {0.f, 0.f, 0.f, 0.f};
    #pragma unroll
    for (int h = 0; h < 2; ++h) {
        #pragma unroll
        for (int rr = 0; rr < 4; ++rr) {
            const int row = b * 32 + h * 16 + w * 4 + rr;   // wave-uniform
            const float* src = (row < NS) ? (S + (size_t)row * DD)
                                          : (T + (size_t)(row - NS) * DD);
            const f32x4 v = *(const f32x4*)(src + lane * 4);
            cacc += v;
            float vv = v.x * v.x + v.y * v.y + v.z * v.z + v.w * v.w;
            half4 hx = { (_Float16)v.x, (_Float16)v.y, (_Float16)v.z, (_Float16)v.w };
            *(half4*)&tile[w * 4 + rr][lane * 4] = hx;
            #pragma unroll
            for (int off = 32; off; off >>= 1) vv += __shfl_down(vv, off);
            if (lane == 0) sq[row] = vv;
        }
        __syncthreads();
        _Float16* dst = X16 + (size_t)(b * 2 + h) * 4096;
        #pragma unroll
        for (int q = 0; q < 2; ++q) {
            const int c = q * 256 + tid;                    // chunk = kc*16+rl
            *(half8*)(dst + c * 8) = *(const half8*)&tile[c & 15][(c >> 4) * 8];
        }
        __syncthreads();
    }
    *(f32x4*)&cl[w][lane * 4] = cacc;
    __syncthreads();
    colpart[b * 256 + tid] = cl[0][tid] + cl[1][tid] + cl[2][tid] + cl[3][tid];
}

// ---------------------------------------------------------------- K2: bandwidth (+sqp fill)
__global__ __launch_bounds__(1024) void mmd_bw(const float* __restrict__ colpart,
                                               const float* __restrict__ sq,
                                               float* __restrict__ scal,
                                               float* __restrict__ sqp) {
    __shared__ float cpart[4][256];
    __shared__ double sd[16], sf[16];
    __shared__ float cl2sh;
    const int t = threadIdx.x;
    const int c = t & 255, g = t >> 8;
    float cs = 0.0f;
    #pragma unroll
    for (int b = 0; b < 64; ++b) cs += colpart[((g * 64 + b) << 8) | c];
    cpart[g][c] = cs;
    const f32x4 q0 = *(const f32x4*)(sq + t * 8);
    const f32x4 q1 = *(const f32x4*)(sq + t * 8 + 4);
    double qd = (double)(q0.x + q0.y + q0.z + q0.w) +
                (double)(q1.x + q1.y + q1.z + q1.w);
    __syncthreads();
    double s2 = 0.0;
    if (g == 0) {
        const double tot = (double)cpart[0][c] + cpart[1][c] +
                           cpart[2][c] + cpart[3][c];
        s2 = tot * tot;
    }
    const int lane = t & 63, w = t >> 6;
    #pragma unroll
    for (int off = 32; off; off >>= 1) {
        s2 += __shfl_down(s2, off);
        qd += __shfl_down(qd, off);
    }
    if (lane == 0) { sd[w] = s2; sf[w] = qd; }
    __syncthreads();
    if (t == 0) {
        double s2t = 0.0, qt = 0.0;
        #pragma unroll
        for (int i = 0; i < 16; ++i) { s2t += sd[i]; qt += sf[i]; }
        const double n = (double)NTOT;
        const double sumd2 = 2.0 * n * qt - 2.0 * s2t;
        double bwv = sumd2 / (n * n - n);
        bwv = bwv / 4.0;   // KERNEL_MUL^(KERNEL_NUM//2) = 2^2
        const float cl2 = (float)(1.0 / (16.0 * bwv * 0.6931471805599453));
        scal[0] = cl2;
        cl2sh = cl2;
    }
    __syncthreads();
    const float mcl2 = -cl2sh;
    #pragma unroll
    for (int k = 0; k < 8; ++k)
        sqp[t + k * 1024] = mcl2 * sq[t + k * 1024];
}

// ---------------------------------------------------------------- K3: main (persistent, 1024 thr)
// 256 blocks = 1 per CU, 16 waves (4/SIMD for latency hiding). Block owns
// ~8 tiles of the br-major list. A-strip (128 rows, full K, 64KB tiled4) in
// LDS once per strip. Waves: g=w>>2 picks tile (4 tiles in flight), (rh,ch)
// 2x2 split of the tile (64x64 per wave: balanced -> LDS-A reads halved).
// B straight from L2 to registers. NO per-tile barriers; per-wave float
// accumulator; one cross-wave reduce at the end. pk-fp16 exp epilogue.
__global__ __launch_bounds__(1024, 4) void mmd_main(const _Float16* __restrict__ X16,
                                                    const float* __restrict__ sqp,
                                                    const float* __restrict__ scal,
                                                    float* __restrict__ blockpart) {
    __shared__ _Float16 As[8 * 4096];      // 64 KB A strip
    __shared__ float sqs[128];             // strip's premultiplied row terms
    __shared__ float wsum[16];

    // T1: XCD swizzle (256 % 8 == 0 -> bijective)
    const int p = (blockIdx.x & 7) * (NPERS / 8) + (blockIdx.x >> 3);
    const int t0 = (65 * p) >> 3, t1 = (65 * (p + 1)) >> 3;

    const int tid = threadIdx.x;
    const int lane = tid & 63, w = tid >> 6;
    const int g = w >> 2;                  // tile group (0..3)
    const int rh = (w >> 1) & 1, ch = w & 1;   // 2x2 split of the tile
    const int rA = lane & 15, hi = lane >> 4;
    const int lof = hi * 128 + rA * 8;     // fragment offset in a 512-elem group

    const float c2 = 2.0f * scal[0];
    const fp16x2 one2 = {(__fp16)1.0f, (__fp16)1.0f};

    int br = 0;
    while (cumtiles(br + 1) <= t0) ++br;
    int Cbr = cumtiles(br);
    int ssize = (br < 32) ? br + 33 : br - 31;

    float waveacc = 0.0f;
    int t = t0;
    while (t < t1) {
        const int segEnd = (t1 < Cbr + ssize) ? t1 : (Cbr + ssize);
        // ---- stage strip br (once) ----
        __syncthreads();                   // previous segment's As reads done
        const _Float16* Ag = X16 + (size_t)(br * 8) * 4096;
        #pragma unroll
        for (int i = 0; i < 4; ++i) {
            const int c = i * 1024 + tid;
            __builtin_amdgcn_global_load_lds(
                (const __attribute__((address_space(1))) uint32_t*)(Ag + c * 8),
                (__attribute__((address_space(3))) uint32_t*)&As[c * 8], 16, 0, 0);
        }
        if (tid < 128) sqs[tid] = sqp[br * 128 + tid];
        asm volatile("s_waitcnt vmcnt(0)" ::: "memory");
        __syncthreads();

        // ---- tiles of this strip: wave-group g takes t+g, t+g+4, ... ----
        for (int tt = t + g; tt < segEnd; tt += 4) {
            const int l = tt - Cbr;
            int bc; float wfac;
            if (br < 32) {
                if (l <= br) { bc = l;               wfac = (bc == br) ? 1.0f : 2.0f; }
                else         { bc = 32 + l - br - 1; wfac = -2.0f; }
            } else         { bc = 32 + l;            wfac = (bc == br) ? 1.0f : 2.0f; }

            const int col0 = bc * 128;
            const _Float16* Bq = X16 + ((size_t)bc * 8 + ch * 4) * 4096 + lof;

            f32x4 acc[4][4] = {};
            #pragma unroll
            for (int kt = 0; kt < 8; ++kt) {
                half8 b[4], a[4];
                #pragma unroll
                for (int nf = 0; nf < 4; ++nf)
                    b[nf] = *(const half8*)(Bq + (size_t)nf * 4096 + kt * 512);
                #pragma unroll
                for (int m = 0; m < 4; ++m)
                    a[m] = *(const half8*)&As[(rh * 4 + m) * 4096 + kt * 512 + lof];
                #pragma unroll
                for (int m = 0; m < 4; ++m)
                    #pragma unroll
                    for (int nf = 0; nf < 4; ++nf)
                        acc[m][nf] = __builtin_amdgcn_mfma_f32_16x16x32_f16(
                            a[m], b[nf], acc[m][nf], 0, 0, 0);
            }

            // epilogue: x = g*2cl2 + sip+sj (<=0); e=2^x; e+e^2+e^4+e^8+e^16
            float sj[4];
            #pragma unroll
            for (int nf = 0; nf < 4; ++nf)
                sj[nf] = sqp[col0 + ch * 64 + nf * 16 + rA];
            float part = 0.0f;
            #pragma unroll
            for (int m = 0; m < 4; ++m) {
                const f32x4 sipv = *(const f32x4*)&sqs[rh * 64 + m * 16 + hi * 4];
                #pragma unroll
                for (int nf = 0; nf < 4; ++nf)
                    #pragma unroll
                    for (int rp = 0; rp < 2; ++rp) {
                        const float x0 = fminf(fmaf(acc[m][nf][2 * rp],     c2,
                                                    sipv[2 * rp]     + sj[nf]), 0.0f);
                        const float x1 = fminf(fmaf(acc[m][nf][2 * rp + 1], c2,
                                                    sipv[2 * rp + 1] + sj[nf]), 0.0f);
                        const float e0 = exp2f(x0);
                        const float e1 = exp2f(x1);
                        fp16x2 h  = __builtin_amdgcn_cvt_pkrtz(e0, e1);
                        fp16x2 p2 = h * h;           // e^2
                        fp16x2 ks = h + p2;
                        p2 = p2 * p2; ks += p2;      // e^4
                        p2 = p2 * p2; ks += p2;      // e^8
                        p2 = p2 * p2; ks += p2;      // e^16
#if __has_builtin(__builtin_amdgcn_fdot2)
                        part = __builtin_amdgcn_fdot2(ks, one2, part, false);
#else
                        part += (float)ks.x + (float)ks.y;
#endif
                    }
            }
            waveacc += wfac * part;
        }
        t = segEnd;
        if (t < t1) { Cbr += ssize; ++br; ssize = (br < 32) ? br + 33 : br - 31; }
    }

    #pragma unroll
    for (int off = 32; off > 0; off >>= 1) waveacc += __shfl_down(waveacc, off);
    if (lane == 0) wsum[w] = waveacc;
    __syncthreads();
    if (tid == 0) {
        float s = 0.0f;
        #pragma unroll
        for (int i = 0; i < 16; ++i) s += wsum[i];
        blockpart[p] = s;
    }
}

// ---------------------------------------------------------------- K4: final reduce
__global__ __launch_bounds__(256) void mmd_final(const float* __restrict__ blockpart,
                                                 float* __restrict__ out) {
    const int t = threadIdx.x;
    double acc = (double)blockpart[t];     // exactly 256 entries
    #pragma unroll
    for (int off = 32; off > 0; off >>= 1) acc += __shfl_down(acc, off);
    __shared__ double sd[4];
    const int lane = t & 63, w = t >> 6;
    if (lane == 0) sd[w] = acc;
    __syncthreads();
    if (t == 0) {
        const double tot = (sd[0] + sd[1] + sd[2] + sd[3]) /
                           ((double)NS * (double)NS);
        out[0] = (float)fmax(tot, 0.0);
    }
}

// ---------------------------------------------------------------- launch
extern "C" void kernel_launch(void* const* d_in, const int* in_sizes, int n_in,
                              void* d_out, int out_size, void* d_ws, size_t ws_size,
                              hipStream_t stream) {
    const float* S = (const float*)d_in[0];
    const float* T = (const float*)d_in[1];
    char* ws = (char*)d_ws;
    _Float16* X16   = (_Float16*)(ws + OFF_X16);
    float* sq       = (float*)(ws + OFF_SQ);
    float* sqp      = (float*)(ws + OFF_SQP);
    float* colpart  = (float*)(ws + OFF_COLP);
    float* blockpart= (float*)(ws + OFF_BP);
    float* scal     = (float*)(ws + OFF_SCAL);

    mmd_prep<<<256, 256, 0, stream>>>(S, T, X16, sq, colpart);
    mmd_bw<<<1, 1024, 0, stream>>>(colpart, sq, scal, sqp);
    mmd_main<<<NPERS, 1024, 0, stream>>>(X16, sqp, scal, blockpart);
    mmd_final<<<1, 256, 0, stream>>>(blockpart, (float*)d_out);
}

// Round 14
// 163.351 us; speedup vs baseline: 1.0122x; 1.0122x over previous
//
#include <hip/hip_runtime.h>
#include <stdint.h>

typedef __fp16 fp16x2 __attribute__((ext_vector_type(2)));
typedef _Float16 half4 __attribute__((ext_vector_type(4)));
typedef _Float16 half8 __attribute__((ext_vector_type(8)));
typedef float f32x4 __attribute__((ext_vector_type(4)));

#define NS 4096
#define NTOT 8192
#define DD 256
#define NPERS 256   // persistent blocks: 1 per CU, 1024 threads (16 waves)

// X16 "tiled4" layout: addr(r,k) = (r>>4)*4096 + (k>>3)*128 + (r&15)*8 + (k&7)
// -> 16-row full-K panel = contiguous 8KB; a 128-row strip = 64KB linear.

// workspace layout (bytes)
#define OFF_X16   0                        // 4 MB fp16 (tiled4)
#define OFF_SQ    (4*1024*1024)            // 8192 floats
#define OFF_SQP   (OFF_SQ + 32*1024)       // 8192 floats: -cl2*sq (premultiplied)
#define OFF_COLP  (OFF_SQP + 32*1024)      // 256*256 floats
#define OFF_BP    (OFF_COLP + 256*1024)    // 256 floats
#define OFF_SCAL  (OFF_BP + 4096)          // 1 float (cl2)

// cumulative tiles before strip br (br<32: SS tri (br+1) then 32 ST;
// br>=32: TT tri (br-31))
__device__ __forceinline__ int cumtiles(int br) {
    return (br <= 32) ? (br * br + 65 * br) / 2
                      : 1552 + ((br - 32) * (br - 31)) / 2;
}

// ---------------------------------------------------------------- K1: prep
__global__ __launch_bounds__(256) void mmd_prep(const float* __restrict__ S,
                                                const float* __restrict__ T,
                                                _Float16* __restrict__ X16,
                                                float* __restrict__ sq,
                                                float* __restrict__ colpart) {
    __shared__ _Float16 tile[16][264];     // +8 halves pad: conflict-free reorder
    __shared__ float cl[4][256];
    const int b = blockIdx.x, tid = threadIdx.x;
    const int lane = tid & 63, w = tid >> 6;
    f32x4 cacc = {0.f, 0.f, 0.f, 0.f};
    #pragma unroll
    for (int h = 0; h < 2; ++h) {
        #pragma unroll
        for (int rr = 0; rr < 4; ++rr) {
            const int row = b * 32 + h * 16 + w * 4 + rr;   // wave-uniform
            const float* src = (row < NS) ? (S + (size_t)row * DD)
                                          : (T + (size_t)(row - NS) * DD);
            const f32x4 v = *(const f32x4*)(src + lane * 4);
            cacc += v;
            float vv = v.x * v.x + v.y * v.y + v.z * v.z + v.w * v.w;
            half4 hx = { (_Float16)v.x, (_Float16)v.y, (_Float16)v.z, (_Float16)v.w };
            *(half4*)&tile[w * 4 + rr][lane * 4] = hx;
            #pragma unroll
            for (int off = 32; off; off >>= 1) vv += __shfl_down(vv, off);
            if (lane == 0) sq[row] = vv;
        }
        __syncthreads();
        _Float16* dst = X16 + (size_t)(b * 2 + h) * 4096;
        #pragma unroll
        for (int q = 0; q < 2; ++q) {
            const int c = q * 256 + tid;                    // chunk = kc*16+rl
            *(half8*)(dst + c * 8) = *(const half8*)&tile[c & 15][(c >> 4) * 8];
        }
        __syncthreads();
    }
    *(f32x4*)&cl[w][lane * 4] = cacc;
    __syncthreads();
    colpart[b * 256 + tid] = cl[0][tid] + cl[1][tid] + cl[2][tid] + cl[3][tid];
}

// ---------------------------------------------------------------- K2: bandwidth (+sqp fill)
__global__ __launch_bounds__(1024) void mmd_bw(const float* __restrict__ colpart,
                                               const float* __restrict__ sq,
                                               float* __restrict__ scal,
                                               float* __restrict__ sqp) {
    __shared__ float cpart[4][256];
    __shared__ double sd[16], sf[16];
    __shared__ float cl2sh;
    const int t = threadIdx.x;
    const int c = t & 255, g = t >> 8;
    float cs = 0.0f;
    #pragma unroll
    for (int b = 0; b < 64; ++b) cs += colpart[((g * 64 + b) << 8) | c];
    cpart[g][c] = cs;
    const f32x4 q0 = *(const f32x4*)(sq + t * 8);
    const f32x4 q1 = *(const f32x4*)(sq + t * 8 + 4);
    double qd = (double)(q0.x + q0.y + q0.z + q0.w) +
                (double)(q1.x + q1.y + q1.z + q1.w);
    __syncthreads();
    double s2 = 0.0;
    if (g == 0) {
        const double tot = (double)cpart[0][c] + cpart[1][c] +
                           cpart[2][c] + cpart[3][c];
        s2 = tot * tot;
    }
    const int lane = t & 63, w = t >> 6;
    #pragma unroll
    for (int off = 32; off; off >>= 1) {
        s2 += __shfl_down(s2, off);
        qd += __shfl_down(qd, off);
    }
    if (lane == 0) { sd[w] = s2; sf[w] = qd; }
    __syncthreads();
    if (t == 0) {
        double s2t = 0.0, qt = 0.0;
        #pragma unroll
        for (int i = 0; i < 16; ++i) { s2t += sd[i]; qt += sf[i]; }
        const double n = (double)NTOT;
        const double sumd2 = 2.0 * n * qt - 2.0 * s2t;
        double bwv = sumd2 / (n * n - n);
        bwv = bwv / 4.0;   // KERNEL_MUL^(KERNEL_NUM//2) = 2^2
        const float cl2 = (float)(1.0 / (16.0 * bwv * 0.6931471805599453));
        scal[0] = cl2;
        cl2sh = cl2;
    }
    __syncthreads();
    const float mcl2 = -cl2sh;
    #pragma unroll
    for (int k = 0; k < 8; ++k)
        sqp[t + k * 1024] = mcl2 * sq[t + k * 1024];
}

// ---------------------------------------------------------------- K3: main (persistent, 1024 thr)
// 256 blocks = 1 per CU, 16 waves = 4/SIMD (launch_bounds(1024,1): VGPR cap
// 128, >64 VGPR blocks runtime co-residency -> exactly 16 waves). 2 tiles in
// flight (g = w>>3), 8 waves per tile: wave = 64 rows x 32 cols, acc[4][2]
// (32 VGPR). A-strip (128 rows full K, 64KB tiled4) in LDS once per strip;
// B straight L2->reg. No per-tile barriers. pk-fp16 exp epilogue.
__global__ __launch_bounds__(1024, 1) void mmd_main(const _Float16* __restrict__ X16,
                                                    const float* __restrict__ sqp,
                                                    const float* __restrict__ scal,
                                                    float* __restrict__ blockpart) {
    __shared__ _Float16 As[8 * 4096];      // 64 KB A strip
    __shared__ float sqs[128];             // strip's premultiplied row terms
    __shared__ float wsum[16];

    // T1: XCD swizzle (256 % 8 == 0 -> bijective)
    const int p = (blockIdx.x & 7) * (NPERS / 8) + (blockIdx.x >> 3);
    const int t0 = (65 * p) >> 3, t1 = (65 * (p + 1)) >> 3;

    const int tid = threadIdx.x;
    const int lane = tid & 63, w = tid >> 6;
    const int g  = w >> 3;                 // tile group (0..1)
    const int w2 = w & 7;
    const int rh = w2 >> 2;                // row half (64 rows)
    const int cq = w2 & 3;                 // col quarter (32 cols)
    const int rA = lane & 15, hi = lane >> 4;
    const int lof = hi * 128 + rA * 8;     // fragment offset in a 512-elem group

    const float c2 = 2.0f * scal[0];
    const fp16x2 one2 = {(__fp16)1.0f, (__fp16)1.0f};

    int br = 0;
    while (cumtiles(br + 1) <= t0) ++br;
    int Cbr = cumtiles(br);
    int ssize = (br < 32) ? br + 33 : br - 31;

    float waveacc = 0.0f;
    int t = t0;
    while (t < t1) {
        const int segEnd = (t1 < Cbr + ssize) ? t1 : (Cbr + ssize);
        // ---- stage strip br (once) ----
        __syncthreads();                   // previous segment's As reads done
        const _Float16* Ag = X16 + (size_t)(br * 8) * 4096;
        #pragma unroll
        for (int i = 0; i < 4; ++i) {
            const int c = i * 1024 + tid;
            __builtin_amdgcn_global_load_lds(
                (const __attribute__((address_space(1))) uint32_t*)(Ag + c * 8),
                (__attribute__((address_space(3))) uint32_t*)&As[c * 8], 16, 0, 0);
        }
        if (tid < 128) sqs[tid] = sqp[br * 128 + tid];
        asm volatile("s_waitcnt vmcnt(0)" ::: "memory");
        __syncthreads();

        // ---- tiles of this strip: group g takes t+g, t+g+2, ... ----
        for (int tt = t + g; tt < segEnd; tt += 2) {
            const int l = tt - Cbr;
            int bc; float wfac;
            if (br < 32) {
                if (l <= br) { bc = l;               wfac = (bc == br) ? 1.0f : 2.0f; }
                else         { bc = 32 + l - br - 1; wfac = -2.0f; }
            } else         { bc = 32 + l;            wfac = (bc == br) ? 1.0f : 2.0f; }

            const int col0 = bc * 128;
            const _Float16* Bq = X16 + ((size_t)bc * 8 + cq * 2) * 4096 + lof;

            f32x4 acc[4][2] = {};
            #pragma unroll
            for (int kt = 0; kt < 8; ++kt) {
                const half8 b0 = *(const half8*)(Bq + kt * 512);
                const half8 b1 = *(const half8*)(Bq + 4096 + kt * 512);
                half8 a[4];
                #pragma unroll
                for (int m = 0; m < 4; ++m)
                    a[m] = *(const half8*)&As[(rh * 4 + m) * 4096 + kt * 512 + lof];
                #pragma unroll
                for (int m = 0; m < 4; ++m) {
                    acc[m][0] = __builtin_amdgcn_mfma_f32_16x16x32_f16(a[m], b0, acc[m][0], 0, 0, 0);
                    acc[m][1] = __builtin_amdgcn_mfma_f32_16x16x32_f16(a[m], b1, acc[m][1], 0, 0, 0);
                }
            }

            // epilogue: x = g*2cl2 + sip+sj (<=0); e=2^x; e+e^2+e^4+e^8+e^16
            const float sj0 = sqp[col0 + cq * 32 + rA];
            const float sj1 = sqp[col0 + cq * 32 + 16 + rA];
            float part = 0.0f;
            #pragma unroll
            for (int m = 0; m < 4; ++m) {
                const f32x4 sipv = *(const f32x4*)&sqs[rh * 64 + m * 16 + hi * 4];
                #pragma unroll
                for (int nf = 0; nf < 2; ++nf) {
                    const float sj = nf ? sj1 : sj0;
                    #pragma unroll
                    for (int rp = 0; rp < 2; ++rp) {
                        const float x0 = fminf(fmaf(acc[m][nf][2 * rp],     c2,
                                                    sipv[2 * rp]     + sj), 0.0f);
                        const float x1 = fminf(fmaf(acc[m][nf][2 * rp + 1], c2,
                                                    sipv[2 * rp + 1] + sj), 0.0f);
                        const float e0 = exp2f(x0);
                        const float e1 = exp2f(x1);
                        fp16x2 h  = __builtin_amdgcn_cvt_pkrtz(e0, e1);
                        fp16x2 p2 = h * h;           // e^2
                        fp16x2 ks = h + p2;
                        p2 = p2 * p2; ks += p2;      // e^4
                        p2 = p2 * p2; ks += p2;      // e^8
                        p2 = p2 * p2; ks += p2;      // e^16
#if __has_builtin(__builtin_amdgcn_fdot2)
                        part = __builtin_amdgcn_fdot2(ks, one2, part, false);
#else
                        part += (float)ks.x + (float)ks.y;
#endif
                    }
                }
            }
            waveacc += wfac * part;
        }
        t = segEnd;
        if (t < t1) { Cbr += ssize; ++br; ssize = (br < 32) ? br + 33 : br - 31; }
    }

    #pragma unroll
    for (int off = 32; off > 0; off >>= 1) waveacc += __shfl_down(waveacc, off);
    if (lane == 0) wsum[w] = waveacc;
    __syncthreads();
    if (tid == 0) {
        float s = 0.0f;
        #pragma unroll
        for (int i = 0; i < 16; ++i) s += wsum[i];
        blockpart[p] = s;
    }
}

// ---------------------------------------------------------------- K4: final reduce
__global__ __launch_bounds__(256) void mmd_final(const float* __restrict__ blockpart,
                                                 float* __restrict__ out) {
    const int t = threadIdx.x;
    double acc = (double)blockpart[t];     // exactly 256 entries
    #pragma unroll
    for (int off = 32; off > 0; off >>= 1) acc += __shfl_down(acc, off);
    __shared__ double sd[4];
    const int lane = t & 63, w = t >> 6;
    if (lane == 0) sd[w] = acc;
    __syncthreads();
    if (t == 0) {
        const double tot = (sd[0] + sd[1] + sd[2] + sd[3]) /
                           ((double)NS * (double)NS);
        out[0] = (float)fmax(tot, 0.0);
    }
}

// ---------------------------------------------------------------- launch
extern "C" void kernel_launch(void* const* d_in, const int* in_sizes, int n_in,
                              void* d_out, int out_size, void* d_ws, size_t ws_size,
                              hipStream_t stream) {
    const float* S = (const float*)d_in[0];
    const float* T = (const float*)d_in[1];
    char* ws = (char*)d_ws;
    _Float16* X16   = (_Float16*)(ws + OFF_X16);
    float* sq       = (float*)(ws + OFF_SQ);
    float* sqp      = (float*)(ws + OFF_SQP);
    float* colpart  = (float*)(ws + OFF_COLP);
    float* blockpart= (float*)(ws + OFF_BP);
    float* scal     = (float*)(ws + OFF_SCAL);

    mmd_prep<<<256, 256, 0, stream>>>(S, T, X16, sq, colpart);
    mmd_bw<<<1, 1024, 0, stream>>>(colpart, sq, scal, sqp);
    mmd_main<<<NPERS, 1024, 0, stream>>>(X16, sqp, scal, blockpart);
    mmd_final<<<1, 256, 0, stream>>>(blockpart, (float*)d_out);
}

// Round 15
// 51.207 us; speedup vs baseline: 3.2289x; 3.1900x over previous
//
#include <hip/hip_runtime.h>
#include <stdint.h>

typedef __fp16 fp16x2 __attribute__((ext_vector_type(2)));
typedef _Float16 half4 __attribute__((ext_vector_type(4)));
typedef _Float16 half8 __attribute__((ext_vector_type(8)));
typedef float f32x4 __attribute__((ext_vector_type(4)));

#define NS 4096
#define NTOT 8192
#define DD 256
#define NBLK 2080   // 128x128 tiles: 528 SS tri + 528 TT tri + 1024 ST

// X16 "tiled4" layout: addr(r,k) = (r>>4)*4096 + (k>>3)*128 + (r&15)*8 + (k&7)
// -> every MFMA fragment (16 rows x 8 k) of a (row-group, kt) is ONE
// contiguous 1KB block: loadable straight from L2 as wave-uniform base +
// lane*16B. This kernel uses NO LDS for operands.

// workspace layout (bytes)
#define OFF_X16   0                        // 4 MB fp16 (tiled4)
#define OFF_SQ    (4*1024*1024)            // 8192 floats
#define OFF_SQP   (OFF_SQ + 32*1024)       // 8192 floats: -cl2*sq
#define OFF_COLP  (OFF_SQP + 32*1024)      // 256*256 floats
#define OFF_BP    (OFF_COLP + 256*1024)    // 2080 floats
#define OFF_SCAL  (OFF_BP + 8320)          // 1 float (cl2)

// ---------------------------------------------------------------- K1: prep
__global__ __launch_bounds__(256) void mmd_prep(const float* __restrict__ S,
                                                const float* __restrict__ T,
                                                _Float16* __restrict__ X16,
                                                float* __restrict__ sq,
                                                float* __restrict__ colpart) {
    __shared__ _Float16 tile[16][264];     // +8 halves pad: conflict-free reorder
    __shared__ float cl[4][256];
    const int b = blockIdx.x, tid = threadIdx.x;
    const int lane = tid & 63, w = tid >> 6;
    f32x4 cacc = {0.f, 0.f, 0.f, 0.f};
    #pragma unroll
    for (int h = 0; h < 2; ++h) {
        #pragma unroll
        for (int rr = 0; rr < 4; ++rr) {
            const int row = b * 32 + h * 16 + w * 4 + rr;   // wave-uniform
            const float* src = (row < NS) ? (S + (size_t)row * DD)
                                          : (T + (size_t)(row - NS) * DD);
            const f32x4 v = *(const f32x4*)(src + lane * 4);
            cacc += v;
            float vv = v.x * v.x + v.y * v.y + v.z * v.z + v.w * v.w;
            half4 hx = { (_Float16)v.x, (_Float16)v.y, (_Float16)v.z, (_Float16)v.w };
            *(half4*)&tile[w * 4 + rr][lane * 4] = hx;
            #pragma unroll
            for (int off = 32; off; off >>= 1) vv += __shfl_down(vv, off);
            if (lane == 0) sq[row] = vv;
        }
        __syncthreads();
        _Float16* dst = X16 + (size_t)(b * 2 + h) * 4096;
        #pragma unroll
        for (int q = 0; q < 2; ++q) {
            const int c = q * 256 + tid;                    // chunk = kc*16+rl
            *(half8*)(dst + c * 8) = *(const half8*)&tile[c & 15][(c >> 4) * 8];
        }
        __syncthreads();
    }
    *(f32x4*)&cl[w][lane * 4] = cacc;
    __syncthreads();
    colpart[b * 256 + tid] = cl[0][tid] + cl[1][tid] + cl[2][tid] + cl[3][tid];
}

// ---------------------------------------------------------------- K2: bandwidth (+sqp fill)
__global__ __launch_bounds__(1024) void mmd_bw(const float* __restrict__ colpart,
                                               const float* __restrict__ sq,
                                               float* __restrict__ scal,
                                               float* __restrict__ sqp) {
    __shared__ float cpart[4][256];
    __shared__ double sd[16], sf[16];
    __shared__ float cl2sh;
    const int t = threadIdx.x;
    const int c = t & 255, g = t >> 8;
    float cs = 0.0f;
    #pragma unroll
    for (int b = 0; b < 64; ++b) cs += colpart[((g * 64 + b) << 8) | c];
    cpart[g][c] = cs;
    const f32x4 q0 = *(const f32x4*)(sq + t * 8);
    const f32x4 q1 = *(const f32x4*)(sq + t * 8 + 4);
    double qd = (double)(q0.x + q0.y + q0.z + q0.w) +
                (double)(q1.x + q1.y + q1.z + q1.w);
    __syncthreads();
    double s2 = 0.0;
    if (g == 0) {
        const double tot = (double)cpart[0][c] + cpart[1][c] +
                           cpart[2][c] + cpart[3][c];
        s2 = tot * tot;
    }
    const int lane = t & 63, w = t >> 6;
    #pragma unroll
    for (int off = 32; off; off >>= 1) {
        s2 += __shfl_down(s2, off);
        qd += __shfl_down(qd, off);
    }
    if (lane == 0) { sd[w] = s2; sf[w] = qd; }
    __syncthreads();
    if (t == 0) {
        double s2t = 0.0, qt = 0.0;
        #pragma unroll
        for (int i = 0; i < 16; ++i) { s2t += sd[i]; qt += sf[i]; }
        const double n = (double)NTOT;
        const double sumd2 = 2.0 * n * qt - 2.0 * s2t;
        double bwv = sumd2 / (n * n - n);
        bwv = bwv / 4.0;   // KERNEL_MUL^(KERNEL_NUM//2) = 2^2
        const float cl2 = (float)(1.0 / (16.0 * bwv * 0.6931471805599453));
        scal[0] = cl2;
        cl2sh = cl2;
    }
    __syncthreads();
    const float mcl2 = -cl2sh;
    #pragma unroll
    for (int k = 0; k < 8; ++k)
        sqp[t + k * 1024] = mcl2 * sq[t + k * 1024];
}

// ---------------------------------------------------------------- K3: main (NO-LDS, pure TLP)
// 2080 blocks x 256 threads (4 waves), 128x128 tile, wave = 64x64 quadrant
// (rh,ch). ALL operand fragments load straight from L2 (tiled4: one coalesced
// 1KB txn per fragment). No LDS, no barriers, no staging -> occupancy bound
// only by VGPR; free wave drift overlaps epilogue VALU with MFMA/L2 of other
// waves. pk-fp16 exp epilogue (proven absmax-0 math).
__global__ __launch_bounds__(256) void mmd_main(const _Float16* __restrict__ X16,
                                                const float* __restrict__ sqp,
                                                const float* __restrict__ scal,
                                                float* __restrict__ blockpart) {
    __shared__ float wsum[4];

    // T1: XCD swizzle (2080 % 8 == 0 -> bijective simple form)
    const int bid = (blockIdx.x & 7) * (NBLK / 8) + (blockIdx.x >> 3);
    int br, bc;
    float wfac;
    if (bid < 1056) {
        int t = bid, base = 0;
        if (t >= 528) { t -= 528; base = 32; }
        int i = (int)((sqrtf(8.0f * (float)t + 1.0f) - 1.0f) * 0.5f);
        while ((i + 1) * (i + 2) / 2 <= t) ++i;
        while (i * (i + 1) / 2 > t) --i;
        const int j = t - i * (i + 1) / 2;
        br = base + i; bc = base + j;
        wfac = (i == j) ? 1.0f : 2.0f;   // off-diag tile counts for (i,j) and (j,i)
    } else {
        const int t = bid - 1056;
        br = t >> 5; bc = 32 + (t & 31);
        wfac = -2.0f;                    // loss has -2*xy
    }
    const int row0 = br * 128, col0 = bc * 128;
    const int tid = threadIdx.x;
    const int lane = tid & 63;
    const int w = tid >> 6;
    const int rh = w >> 1, ch = w & 1;     // 2x2 wave split: 64x64 each
    const int rA = lane & 15, hi = lane >> 4;
    const int lof = hi * 128 + rA * 8;     // fragment offset in a 512-elem group

    const _Float16* Abase = X16 + ((size_t)(row0 >> 4) + rh * 4) * 4096 + lof;
    const _Float16* Bbase = X16 + ((size_t)(col0 >> 4) + ch * 4) * 4096 + lof;

    f32x4 acc[4][4] = {};
    #pragma unroll
    for (int kt = 0; kt < 8; ++kt) {
        half8 a[4], b[4];
        #pragma unroll
        for (int m = 0; m < 4; ++m)
            a[m] = *(const half8*)(Abase + (size_t)m * 4096 + kt * 512);
        #pragma unroll
        for (int n = 0; n < 4; ++n)
            b[n] = *(const half8*)(Bbase + (size_t)n * 4096 + kt * 512);
        #pragma unroll
        for (int m = 0; m < 4; ++m)
            #pragma unroll
            for (int n = 0; n < 4; ++n)
                acc[m][n] = __builtin_amdgcn_mfma_f32_16x16x32_f16(
                    a[m], b[n], acc[m][n], 0, 0, 0);
    }

    // epilogue: x = g*2cl2 + sip+sj (<=0); e = 2^x; sum e+e^2+e^4+e^8+e^16
    const float c2 = 2.0f * scal[0];
    const fp16x2 one2 = {(__fp16)1.0f, (__fp16)1.0f};
    float sj[4];
    #pragma unroll
    for (int nf = 0; nf < 4; ++nf)
        sj[nf] = sqp[col0 + ch * 64 + nf * 16 + rA];

    float part = 0.0f;
    #pragma unroll
    for (int m = 0; m < 4; ++m) {
        const f32x4 sipv = *(const f32x4*)&sqp[row0 + rh * 64 + m * 16 + hi * 4];
        #pragma unroll
        for (int nf = 0; nf < 4; ++nf)
            #pragma unroll
            for (int rp = 0; rp < 2; ++rp) {
                const float x0 = fminf(fmaf(acc[m][nf][2 * rp],     c2,
                                            sipv[2 * rp]     + sj[nf]), 0.0f);
                const float x1 = fminf(fmaf(acc[m][nf][2 * rp + 1], c2,
                                            sipv[2 * rp + 1] + sj[nf]), 0.0f);
                const float e0 = exp2f(x0);
                const float e1 = exp2f(x1);
                fp16x2 h  = __builtin_amdgcn_cvt_pkrtz(e0, e1);
                fp16x2 p2 = h * h;           // e^2
                fp16x2 ks = h + p2;
                p2 = p2 * p2; ks += p2;      // e^4
                p2 = p2 * p2; ks += p2;      // e^8
                p2 = p2 * p2; ks += p2;      // e^16
#if __has_builtin(__builtin_amdgcn_fdot2)
                part = __builtin_amdgcn_fdot2(ks, one2, part, false);
#else
                part += (float)ks.x + (float)ks.y;
#endif
            }
    }

    #pragma unroll
    for (int off = 32; off > 0; off >>= 1) part += __shfl_down(part, off);
    if (lane == 0) wsum[w] = part;
    __syncthreads();
    if (tid == 0)
        blockpart[bid] = (wsum[0] + wsum[1] + wsum[2] + wsum[3]) * wfac;
}

// ---------------------------------------------------------------- K4: final reduce
__global__ __launch_bounds__(512) void mmd_final(const float* __restrict__ blockpart,
                                                 float* __restrict__ out) {
    const int t = threadIdx.x;
    double acc = 0.0;
    #pragma unroll
    for (int u = 0; u < 4; ++u) acc += (double)blockpart[t + u * 512];
    if (t < NBLK - 2048) acc += (double)blockpart[t + 2048];
    #pragma unroll
    for (int off = 32; off > 0; off >>= 1) acc += __shfl_down(acc, off);
    __shared__ double sd[8];
    const int lane = t & 63, w = t >> 6;
    if (lane == 0) sd[w] = acc;
    __syncthreads();
    if (t == 0) {
        double tot = 0.0;
        #pragma unroll
        for (int i = 0; i < 8; ++i) tot += sd[i];
        tot /= ((double)NS * (double)NS);
        out[0] = (float)fmax(tot, 0.0);
    }
}

// ---------------------------------------------------------------- launch
extern "C" void kernel_launch(void* const* d_in, const int* in_sizes, int n_in,
                              void* d_out, int out_size, void* d_ws, size_t ws_size,
                              hipStream_t stream) {
    const float* S = (const float*)d_in[0];
    const float* T = (const float*)d_in[1];
    char* ws = (char*)d_ws;
    _Float16* X16   = (_Float16*)(ws + OFF_X16);
    float* sq       = (float*)(ws + OFF_SQ);
    float* sqp      = (float*)(ws + OFF_SQP);
    float* colpart  = (float*)(ws + OFF_COLP);
    float* blockpart= (float*)(ws + OFF_BP);
    float* scal     = (float*)(ws + OFF_SCAL);

    mmd_prep<<<256, 256, 0, stream>>>(S, T, X16, sq, colpart);
    mmd_bw<<<1, 1024, 0, stream>>>(colpart, sq, scal, sqp);
    mmd_main<<<NBLK, 256, 0, stream>>>(X16, sqp, scal, blockpart);
    mmd_final<<<1, 512, 0, stream>>>(blockpart, (float*)d_out);
}

// Round 16
// 51.095 us; speedup vs baseline: 3.2360x; 1.0022x over previous
//
#include <hip/hip_runtime.h>
#include <stdint.h>

typedef __fp16 fp16x2 __attribute__((ext_vector_type(2)));
typedef _Float16 half4 __attribute__((ext_vector_type(4)));
typedef _Float16 half8 __attribute__((ext_vector_type(8)));
typedef float f32x4 __attribute__((ext_vector_type(4)));

#define NS 4096
#define NTOT 8192
#define DD 256
#define NBLK 2080   // 128x128 tiles: 528 SS tri + 528 TT tri + 1024 ST

// X16 "tiled4" layout: addr(r,k) = (r>>4)*4096 + (k>>3)*128 + (r&15)*8 + (k&7)
// -> every MFMA fragment (16 rows x 8 k) is ONE contiguous 1KB block:
// loaded straight from L2 as wave-uniform base + lane*16B. NO operand LDS.

// workspace layout (bytes)
#define OFF_X16   0                        // 4 MB fp16 (tiled4)
#define OFF_SQ    (4*1024*1024)            // 8192 floats
#define OFF_SQP   (OFF_SQ + 32*1024)       // 8192 floats: -cl2*sq
#define OFF_COLP  (OFF_SQP + 32*1024)      // 256*256 floats
#define OFF_BP    (OFF_COLP + 256*1024)    // 2080 floats
#define OFF_SCAL  (OFF_BP + 8320)          // 1 float (cl2)

// ---------------------------------------------------------------- K1: prep
__global__ __launch_bounds__(256) void mmd_prep(const float* __restrict__ S,
                                                const float* __restrict__ T,
                                                _Float16* __restrict__ X16,
                                                float* __restrict__ sq,
                                                float* __restrict__ colpart) {
    __shared__ _Float16 tile[16][264];     // +8 halves pad: conflict-free reorder
    __shared__ float cl[4][256];
    const int b = blockIdx.x, tid = threadIdx.x;
    const int lane = tid & 63, w = tid >> 6;
    f32x4 cacc = {0.f, 0.f, 0.f, 0.f};
    #pragma unroll
    for (int h = 0; h < 2; ++h) {
        #pragma unroll
        for (int rr = 0; rr < 4; ++rr) {
            const int row = b * 32 + h * 16 + w * 4 + rr;   // wave-uniform
            const float* src = (row < NS) ? (S + (size_t)row * DD)
                                          : (T + (size_t)(row - NS) * DD);
            const f32x4 v = *(const f32x4*)(src + lane * 4);
            cacc += v;
            float vv = v.x * v.x + v.y * v.y + v.z * v.z + v.w * v.w;
            half4 hx = { (_Float16)v.x, (_Float16)v.y, (_Float16)v.z, (_Float16)v.w };
            *(half4*)&tile[w * 4 + rr][lane * 4] = hx;
            #pragma unroll
            for (int off = 32; off; off >>= 1) vv += __shfl_down(vv, off);
            if (lane == 0) sq[row] = vv;
        }
        __syncthreads();
        _Float16* dst = X16 + (size_t)(b * 2 + h) * 4096;
        #pragma unroll
        for (int q = 0; q < 2; ++q) {
            const int c = q * 256 + tid;                    // chunk = kc*16+rl
            *(half8*)(dst + c * 8) = *(const half8*)&tile[c & 15][(c >> 4) * 8];
        }
        __syncthreads();
    }
    *(f32x4*)&cl[w][lane * 4] = cacc;
    __syncthreads();
    colpart[b * 256 + tid] = cl[0][tid] + cl[1][tid] + cl[2][tid] + cl[3][tid];
}

// ---------------------------------------------------------------- K2: bandwidth (+sqp fill)
__global__ __launch_bounds__(1024) void mmd_bw(const float* __restrict__ colpart,
                                               const float* __restrict__ sq,
                                               float* __restrict__ scal,
                                               float* __restrict__ sqp) {
    __shared__ float cpart[4][256];
    __shared__ double sd[16], sf[16];
    __shared__ float cl2sh;
    const int t = threadIdx.x;
    const int c = t & 255, g = t >> 8;
    float cs = 0.0f;
    #pragma unroll
    for (int b = 0; b < 64; ++b) cs += colpart[((g * 64 + b) << 8) | c];
    cpart[g][c] = cs;
    const f32x4 q0 = *(const f32x4*)(sq + t * 8);
    const f32x4 q1 = *(const f32x4*)(sq + t * 8 + 4);
    double qd = (double)(q0.x + q0.y + q0.z + q0.w) +
                (double)(q1.x + q1.y + q1.z + q1.w);
    __syncthreads();
    double s2 = 0.0;
    if (g == 0) {
        const double tot = (double)cpart[0][c] + cpart[1][c] +
                           cpart[2][c] + cpart[3][c];
        s2 = tot * tot;
    }
    const int lane = t & 63, w = t >> 6;
    #pragma unroll
    for (int off = 32; off; off >>= 1) {
        s2 += __shfl_down(s2, off);
        qd += __shfl_down(qd, off);
    }
    if (lane == 0) { sd[w] = s2; sf[w] = qd; }
    __syncthreads();
    if (t == 0) {
        double s2t = 0.0, qt = 0.0;
        #pragma unroll
        for (int i = 0; i < 16; ++i) { s2t += sd[i]; qt += sf[i]; }
        const double n = (double)NTOT;
        const double sumd2 = 2.0 * n * qt - 2.0 * s2t;
        double bwv = sumd2 / (n * n - n);
        bwv = bwv / 4.0;   // KERNEL_MUL^(KERNEL_NUM//2) = 2^2
        const float cl2 = (float)(1.0 / (16.0 * bwv * 0.6931471805599453));
        scal[0] = cl2;
        cl2sh = cl2;
    }
    __syncthreads();
    const float mcl2 = -cl2sh;
    #pragma unroll
    for (int k = 0; k < 8; ++k)
        sqp[t + k * 1024] = mcl2 * sq[t + k * 1024];
}

// ---------------------------------------------------------------- K3: main (NO-LDS, pure TLP)
// 2080 blocks x 256 threads (4 waves), 128x128 tile, wave = 64x64 quadrant.
// All operands straight from L2 (tiled4 1KB coalesced fragments). No LDS, no
// barriers. launch_bounds(256,4): 4 waves/EU -> VGPR<=128 -> 16 waves/CU
// (the m69 cliff at 128 VGPR was halving occupancy in r15). T5 setprio
// around each MFMA cluster (free-drift waves = role diversity).
__global__ __launch_bounds__(256, 4) void mmd_main(const _Float16* __restrict__ X16,
                                                   const float* __restrict__ sqp,
                                                   const float* __restrict__ scal,
                                                   float* __restrict__ blockpart) {
    __shared__ float wsum[4];

    // T1: XCD swizzle (2080 % 8 == 0 -> bijective simple form)
    const int bid = (blockIdx.x & 7) * (NBLK / 8) + (blockIdx.x >> 3);
    int br, bc;
    float wfac;
    if (bid < 1056) {
        int t = bid, base = 0;
        if (t >= 528) { t -= 528; base = 32; }
        int i = (int)((sqrtf(8.0f * (float)t + 1.0f) - 1.0f) * 0.5f);
        while ((i + 1) * (i + 2) / 2 <= t) ++i;
        while (i * (i + 1) / 2 > t) --i;
        const int j = t - i * (i + 1) / 2;
        br = base + i; bc = base + j;
        wfac = (i == j) ? 1.0f : 2.0f;   // off-diag tile counts for (i,j) and (j,i)
    } else {
        const int t = bid - 1056;
        br = t >> 5; bc = 32 + (t & 31);
        wfac = -2.0f;                    // loss has -2*xy
    }
    const int row0 = br * 128, col0 = bc * 128;
    const int tid = threadIdx.x;
    const int lane = tid & 63;
    const int w = tid >> 6;
    const int rh = w >> 1, ch = w & 1;     // 2x2 wave split: 64x64 each
    const int rA = lane & 15, hi = lane >> 4;
    const int lof = hi * 128 + rA * 8;     // fragment offset in a 512-elem group

    const _Float16* Abase = X16 + ((size_t)(row0 >> 4) + rh * 4) * 4096 + lof;
    const _Float16* Bbase = X16 + ((size_t)(col0 >> 4) + ch * 4) * 4096 + lof;

    f32x4 acc[4][4] = {};
    #pragma unroll
    for (int kt = 0; kt < 8; ++kt) {
        half8 a[4], b[4];
        #pragma unroll
        for (int m = 0; m < 4; ++m)
            a[m] = *(const half8*)(Abase + (size_t)m * 4096 + kt * 512);
        #pragma unroll
        for (int n = 0; n < 4; ++n)
            b[n] = *(const half8*)(Bbase + (size_t)n * 4096 + kt * 512);
        __builtin_amdgcn_s_setprio(1);
        #pragma unroll
        for (int m = 0; m < 4; ++m)
            #pragma unroll
            for (int n = 0; n < 4; ++n)
                acc[m][n] = __builtin_amdgcn_mfma_f32_16x16x32_f16(
                    a[m], b[n], acc[m][n], 0, 0, 0);
        __builtin_amdgcn_s_setprio(0);
    }

    // epilogue: x = g*2cl2 + sip+sj (<=0); e = 2^x; sum e+e^2+e^4+e^8+e^16
    const float c2 = 2.0f * scal[0];
    const fp16x2 one2 = {(__fp16)1.0f, (__fp16)1.0f};
    float sj[4];
    #pragma unroll
    for (int nf = 0; nf < 4; ++nf)
        sj[nf] = sqp[col0 + ch * 64 + nf * 16 + rA];

    float part = 0.0f;
    #pragma unroll
    for (int m = 0; m < 4; ++m) {
        const f32x4 sipv = *(const f32x4*)&sqp[row0 + rh * 64 + m * 16 + hi * 4];
        #pragma unroll
        for (int nf = 0; nf < 4; ++nf)
            #pragma unroll
            for (int rp = 0; rp < 2; ++rp) {
                const float x0 = fminf(fmaf(acc[m][nf][2 * rp],     c2,
                                            sipv[2 * rp]     + sj[nf]), 0.0f);
                const float x1 = fminf(fmaf(acc[m][nf][2 * rp + 1], c2,
                                            sipv[2 * rp + 1] + sj[nf]), 0.0f);
                const float e0 = exp2f(x0);
                const float e1 = exp2f(x1);
                fp16x2 h  = __builtin_amdgcn_cvt_pkrtz(e0, e1);
                fp16x2 p2 = h * h;           // e^2
                fp16x2 ks = h + p2;
                p2 = p2 * p2; ks += p2;      // e^4
                p2 = p2 * p2; ks += p2;      // e^8
                p2 = p2 * p2; ks += p2;      // e^16
#if __has_builtin(__builtin_amdgcn_fdot2)
                part = __builtin_amdgcn_fdot2(ks, one2, part, false);
#else
                part += (float)ks.x + (float)ks.y;
#endif
            }
    }

    #pragma unroll
    for (int off = 32; off > 0; off >>= 1) part += __shfl_down(part, off);
    if (lane == 0) wsum[w] = part;
    __syncthreads();
    if (tid == 0)
        blockpart[bid] = (wsum[0] + wsum[1] + wsum[2] + wsum[3]) * wfac;
}

// ---------------------------------------------------------------- K4: final reduce
__global__ __launch_bounds__(512) void mmd_final(const float* __restrict__ blockpart,
                                                 float* __restrict__ out) {
    const int t = threadIdx.x;
    double acc = 0.0;
    #pragma unroll
    for (int u = 0; u < 4; ++u) acc += (double)blockpart[t + u * 512];
    if (t < NBLK - 2048) acc += (double)blockpart[t + 2048];
    #pragma unroll
    for (int off = 32; off > 0; off >>= 1) acc += __shfl_down(acc, off);
    __shared__ double sd[8];
    const int lane = t & 63, w = t >> 6;
    if (lane == 0) sd[w] = acc;
    __syncthreads();
    if (t == 0) {
        double tot = 0.0;
        #pragma unroll
        for (int i = 0; i < 8; ++i) tot += sd[i];
        tot /= ((double)NS * (double)NS);
        out[0] = (float)fmax(tot, 0.0);
    }
}

// ---------------------------------------------------------------- launch
extern "C" void kernel_launch(void* const* d_in, const int* in_sizes, int n_in,
                              void* d_out, int out_size, void* d_ws, size_t ws_size,
                              hipStream_t stream) {
    const float* S = (const float*)d_in[0];
    const float* T = (const float*)d_in[1];
    char* ws = (char*)d_ws;
    _Float16* X16   = (_Float16*)(ws + OFF_X16);
    float* sq       = (float*)(ws + OFF_SQ);
    float* sqp      = (float*)(ws + OFF_SQP);
    float* colpart  = (float*)(ws + OFF_COLP);
    float* blockpart= (float*)(ws + OFF_BP);
    float* scal     = (float*)(ws + OFF_SCAL);

    mmd_prep<<<256, 256, 0, stream>>>(S, T, X16, sq, colpart);
    mmd_bw<<<1, 1024, 0, stream>>>(colpart, sq, scal, sqp);
    mmd_main<<<NBLK, 256, 0, stream>>>(X16, sqp, scal, blockpart);
    mmd_final<<<1, 512, 0, stream>>>(blockpart, (float*)d_out);
}